// Round 1
// baseline (207.398 us; speedup 1.0000x reference)
//
#include <hip/hip_runtime.h>
#include <stdint.h>

#define EPS 1e-8f

typedef __attribute__((ext_vector_type(8))) __bf16 bf16x8;
typedef __attribute__((ext_vector_type(4))) float f32x4;

static constexpr int BO = 6400;   // B*O
static constexpr int AA = 16;     // attributes
static constexpr int DD = 1024;   // D
static constexpr int HH = 512;    // H

// ---------- helpers ----------
__device__ __forceinline__ unsigned short f2bf(float x) {
    uint32_t b = __float_as_uint(x);
    b += 0x7fffu + ((b >> 16) & 1u);   // round-to-nearest-even (finite inputs)
    return (unsigned short)(b >> 16);
}

__device__ __forceinline__ float bf2f(unsigned short u) {
    return __uint_as_float(((uint32_t)u) << 16);
}

__device__ __forceinline__ float fast_tanh(float x) {
    // tanh(x) = 1 - 2/(exp(2x)+1); exp overflow -> inf -> rcp -> 0 -> +1 (correct)
    float e = __expf(2.0f * x);
    return 1.0f - __fdividef(2.0f, e + 1.0f);
}

// ---------- kernel 1: f32 -> bf16 staging of obj_vecs and W_obj ----------
__global__ __launch_bounds__(256) void k_prep(const float* __restrict__ obj,
                                              const float* __restrict__ W,
                                              unsigned short* __restrict__ obj_bf,
                                              unsigned short* __restrict__ W_bf) {
    const int n_obj8 = BO * DD / 8;   // 819200
    const int n_w8   = HH * DD / 8;   // 65536
    int i = blockIdx.x * 256 + threadIdx.x;
    if (i >= n_obj8 + n_w8) return;
    const float* src;
    unsigned short* dst;
    long off;
    if (i < n_obj8) { src = obj; dst = obj_bf; off = (long)i * 8; }
    else           { src = W;   dst = W_bf;   off = (long)(i - n_obj8) * 8; }
    float4 v0 = *(const float4*)(src + off);
    float4 v1 = *(const float4*)(src + off + 4);
    union { unsigned short u[8]; int4 v; } pk;
    pk.u[0] = f2bf(v0.x); pk.u[1] = f2bf(v0.y); pk.u[2] = f2bf(v0.z); pk.u[3] = f2bf(v0.w);
    pk.u[4] = f2bf(v1.x); pk.u[5] = f2bf(v1.y); pk.u[6] = f2bf(v1.z); pk.u[7] = f2bf(v1.w);
    *(int4*)(dst + off) = pk.v;
}

// ---------- kernel 2: att_obj[6400][512] = obj @ W^T + b_obj (bf16 MFMA) ----------
// block = 256 threads = 4 waves; output tile 64(M) x 64(N); wave w owns rows [w*16, w*16+16)
__global__ __launch_bounds__(256) void k_gemm(const unsigned short* __restrict__ obj_bf, // [6400][1024]
                                              const unsigned short* __restrict__ W_bf,   // [512][1024]
                                              const float* __restrict__ b_obj,           // [512]
                                              unsigned short* __restrict__ att_obj) {    // [6400][512] bf16
    const int tid  = threadIdx.x;
    const int wv   = tid >> 6;
    const int lane = tid & 63;
    const int lr   = lane & 15;          // A row-in-tile / B col-in-tile
    const int lk   = (lane >> 4) * 8;    // k offset within K=32 step
    const int mt   = blockIdx.x >> 3;    // 0..99
    const int nt   = blockIdx.x & 7;     // 0..7
    const int m0   = mt * 64 + wv * 16;
    const int n0   = nt * 64;

    const unsigned short* ap = obj_bf + (size_t)(m0 + lr) * DD + lk;
    const unsigned short* bp = W_bf   + (size_t)(n0 + lr) * DD + lk;

    f32x4 acc0 = {0.f, 0.f, 0.f, 0.f};
    f32x4 acc1 = acc0, acc2 = acc0, acc3 = acc0;

    #pragma unroll 4
    for (int k0 = 0; k0 < DD; k0 += 32) {
        bf16x8 a  = *(const bf16x8*)(ap + k0);
        bf16x8 b0 = *(const bf16x8*)(bp + k0);
        bf16x8 b1 = *(const bf16x8*)(bp + 16 * DD + k0);
        bf16x8 b2 = *(const bf16x8*)(bp + 32 * DD + k0);
        bf16x8 b3 = *(const bf16x8*)(bp + 48 * DD + k0);
        acc0 = __builtin_amdgcn_mfma_f32_16x16x32_bf16(a, b0, acc0, 0, 0, 0);
        acc1 = __builtin_amdgcn_mfma_f32_16x16x32_bf16(a, b1, acc1, 0, 0, 0);
        acc2 = __builtin_amdgcn_mfma_f32_16x16x32_bf16(a, b2, acc2, 0, 0, 0);
        acc3 = __builtin_amdgcn_mfma_f32_16x16x32_bf16(a, b3, acc3, 0, 0, 0);
    }

    // C/D layout (verified on gfx950): col = lane&15, row = (lane>>4)*4 + reg
    const int crow = (lane >> 4) * 4;
    f32x4 accs[4] = {acc0, acc1, acc2, acc3};
    #pragma unroll
    for (int j = 0; j < 4; ++j) {
        const int n = n0 + j * 16 + lr;
        const float bb = b_obj[n];
        #pragma unroll
        for (int r = 0; r < 4; ++r) {
            att_obj[(size_t)(m0 + crow + r) * HH + n] = f2bf(accs[j][r] + bb);
        }
    }
}

// ---------- kernel 3: fused tanh-score + softmax + masked renorm + pooling ----------
// one block (256 thr) per (b,o) row
__global__ __launch_bounds__(256) void k_attn(const unsigned short* __restrict__ att_obj, // [6400][512] bf16
                                              const float* __restrict__ p_attr,           // [6400][16][512]
                                              const int* __restrict__ masks,              // [6400][16]
                                              const float* __restrict__ w_alpha,          // [512]
                                              const float* __restrict__ attr_feats,       // [6400][16][1024]
                                              float* __restrict__ out) {                  // [6400][1024]
    __shared__ float s_att[HH];
    __shared__ float s_scores[AA];

    const int row = blockIdx.x;
    const int tid = threadIdx.x;

    // stage att_obj row (bf16 -> f32) into LDS
    {
        const unsigned short* ar = att_obj + (size_t)row * HH;
        for (int i = tid; i < HH; i += 256) s_att[i] = bf2f(ar[i]);
    }
    __syncthreads();

    const int wv   = tid >> 6;
    const int lane = tid & 63;
    const int a    = wv * 4 + (lane >> 4);  // attribute index, 0..15
    const int g    = lane & 15;             // 16 lanes per attribute

    // phase 1: score_a = sum_h w_alpha[h]*tanh(p[a][h] + att[h])
    // lane g covers h = jj*64 + g*4 + {0..3}, jj=0..7  (coalesced global, 2-way LDS = free)
    const float4* p4  = (const float4*)(p_attr + ((size_t)row * AA + a) * HH);
    const float4* sa4 = (const float4*)s_att;
    const float4* wa4 = (const float4*)w_alpha;
    float sum = 0.f;
    #pragma unroll
    for (int jj = 0; jj < 8; ++jj) {
        float4 pv = p4[jj * 16 + g];
        float4 av = sa4[jj * 16 + g];
        float4 wvv = wa4[jj * 16 + g];
        sum += wvv.x * fast_tanh(pv.x + av.x);
        sum += wvv.y * fast_tanh(pv.y + av.y);
        sum += wvv.z * fast_tanh(pv.z + av.z);
        sum += wvv.w * fast_tanh(pv.w + av.w);
    }
    sum += __shfl_xor(sum, 1);
    sum += __shfl_xor(sum, 2);
    sum += __shfl_xor(sum, 4);
    sum += __shfl_xor(sum, 8);
    if (g == 0) s_scores[a] = sum;
    __syncthreads();

    // phase 2: softmax over A=16 + mask + renorm (b_alpha is a uniform shift -> cancels)
    float sc[AA];
    float mx = -1e30f;
    #pragma unroll
    for (int i = 0; i < AA; ++i) { sc[i] = s_scores[i]; mx = fmaxf(mx, sc[i]); }
    float S = 0.f;
    #pragma unroll
    for (int i = 0; i < AA; ++i) { sc[i] = __expf(sc[i] - mx); S += sc[i]; }
    const int* mrow = masks + (size_t)row * AA;
    float T = 0.f;
    float wgt[AA];
    #pragma unroll
    for (int i = 0; i < AA; ++i) { wgt[i] = sc[i] * (float)mrow[i]; T += wgt[i]; }
    // softmax -> *mask -> /(sum+EPS)  ==  e_i*m_i / (T + EPS*S)
    const float inv = 1.0f / (T + EPS * S);
    #pragma unroll
    for (int i = 0; i < AA; ++i) wgt[i] *= inv;

    // phase 3: out[d] = sum_a wgt[a] * attr_feats[a][d]; thread t owns float4 #t
    const float4* af4 = (const float4*)(attr_feats + (size_t)row * AA * DD);
    float4 acc = {0.f, 0.f, 0.f, 0.f};
    #pragma unroll
    for (int i = 0; i < AA; ++i) {
        float4 v = af4[(size_t)i * (DD / 4) + tid];
        acc.x += wgt[i] * v.x;
        acc.y += wgt[i] * v.y;
        acc.z += wgt[i] * v.z;
        acc.w += wgt[i] * v.w;
    }
    ((float4*)out)[(size_t)row * (DD / 4) + tid] = acc;
}

extern "C" void kernel_launch(void* const* d_in, const int* in_sizes, int n_in,
                              void* d_out, int out_size, void* d_ws, size_t ws_size,
                              hipStream_t stream) {
    const float* obj_vecs   = (const float*)d_in[0];
    const float* attr_feats = (const float*)d_in[1];
    const float* p_attr     = (const float*)d_in[2];
    const int*   masks      = (const int*)d_in[3];
    const float* W_obj      = (const float*)d_in[4];
    const float* b_obj      = (const float*)d_in[5];
    const float* w_alpha    = (const float*)d_in[6];
    // d_in[7] = b_alpha: uniform additive shift before softmax -> cancels exactly
    float* out = (float*)d_out;

    char* ws = (char*)d_ws;
    unsigned short* att_obj = (unsigned short*)ws;                          // 6,553,600 B
    unsigned short* obj_bf  = (unsigned short*)(ws + 6553600);              // 13,107,200 B
    unsigned short* W_bf    = (unsigned short*)(ws + 6553600 + 13107200);   // 1,048,576 B
    // total ws use: 20,709,376 B

    k_prep<<<3456, 256, 0, stream>>>(obj_vecs, W_obj, obj_bf, W_bf);
    k_gemm<<<800, 256, 0, stream>>>(obj_bf, W_bf, b_obj, att_obj);
    k_attn<<<BO, 256, 0, stream>>>(att_obj, p_attr, masks, w_alpha, attr_feats, out);
}

// Round 2
// 177.715 us; speedup vs baseline: 1.1670x; 1.1670x over previous
//
#include <hip/hip_runtime.h>
#include <stdint.h>

#define EPS 1e-8f

typedef __attribute__((ext_vector_type(8))) __bf16 bf16x8;
typedef __attribute__((ext_vector_type(4))) float f32x4;

static constexpr int BO = 6400;   // B*O
static constexpr int AA = 16;     // attributes
static constexpr int DD = 1024;   // D
static constexpr int HH = 512;    // H

// ---------- helpers ----------
__device__ __forceinline__ unsigned short f2bf(float x) {
    uint32_t b = __float_as_uint(x);
    b += 0x7fffu + ((b >> 16) & 1u);   // round-to-nearest-even (finite inputs)
    return (unsigned short)(b >> 16);
}

__device__ __forceinline__ float fast_tanh(float x) {
    // tanh(x) = 1 - 2/(exp(2x)+1); exp overflow -> inf -> rcp -> 0 -> +1 (correct)
    float e = __expf(2.0f * x);
    return 1.0f - __fdividef(2.0f, e + 1.0f);
}

// ---------- kernel 1: f32 -> bf16 staging of obj_vecs and W_obj ----------
__global__ __launch_bounds__(256) void k_prep(const float* __restrict__ obj,
                                              const float* __restrict__ W,
                                              unsigned short* __restrict__ obj_bf,
                                              unsigned short* __restrict__ W_bf) {
    const int n_obj8 = BO * DD / 8;   // 819200
    const int n_w8   = HH * DD / 8;   // 65536
    int i = blockIdx.x * 256 + threadIdx.x;
    if (i >= n_obj8 + n_w8) return;
    const float* src;
    unsigned short* dst;
    long off;
    if (i < n_obj8) { src = obj; dst = obj_bf; off = (long)i * 8; }
    else           { src = W;   dst = W_bf;   off = (long)(i - n_obj8) * 8; }
    float4 v0 = *(const float4*)(src + off);
    float4 v1 = *(const float4*)(src + off + 4);
    union { unsigned short u[8]; int4 v; } pk;
    pk.u[0] = f2bf(v0.x); pk.u[1] = f2bf(v0.y); pk.u[2] = f2bf(v0.z); pk.u[3] = f2bf(v0.w);
    pk.u[4] = f2bf(v1.x); pk.u[5] = f2bf(v1.y); pk.u[6] = f2bf(v1.z); pk.u[7] = f2bf(v1.w);
    *(int4*)(dst + off) = pk.v;
}

// ---------- kernel 2: att_obj[6400][512] = obj @ W^T + b_obj, f32 out ----------
// one wave (64 thr) per block; wave computes a 64(M) x 64(N) tile: 4x4 MFMA frags
__global__ __launch_bounds__(64) void k_gemm(const unsigned short* __restrict__ obj_bf, // [6400][1024] bf16
                                             const unsigned short* __restrict__ W_bf,   // [512][1024]  bf16
                                             const float* __restrict__ b_obj,           // [512]
                                             float* __restrict__ att_obj) {             // [6400][512]  f32
    const int lane = threadIdx.x;
    const int mt   = blockIdx.x >> 3;    // 0..99
    const int nt   = blockIdx.x & 7;     // 0..7
    const int m0   = mt * 64;
    const int n0   = nt * 64;
    const int lr   = lane & 15;
    const int lk   = (lane >> 4) * 8;

    const unsigned short* ap = obj_bf + (size_t)(m0 + lr) * DD + lk;
    const unsigned short* bp = W_bf   + (size_t)(n0 + lr) * DD + lk;

    f32x4 acc[4][4];
    #pragma unroll
    for (int i = 0; i < 4; ++i)
        #pragma unroll
        for (int j = 0; j < 4; ++j) acc[i][j] = f32x4{0.f, 0.f, 0.f, 0.f};

    #pragma unroll 2
    for (int k0 = 0; k0 < DD; k0 += 32) {
        bf16x8 a[4], b[4];
        #pragma unroll
        for (int i = 0; i < 4; ++i) a[i] = *(const bf16x8*)(ap + (size_t)i * 16 * DD + k0);
        #pragma unroll
        for (int j = 0; j < 4; ++j) b[j] = *(const bf16x8*)(bp + (size_t)j * 16 * DD + k0);
        #pragma unroll
        for (int i = 0; i < 4; ++i)
            #pragma unroll
            for (int j = 0; j < 4; ++j)
                acc[i][j] = __builtin_amdgcn_mfma_f32_16x16x32_bf16(a[i], b[j], acc[i][j], 0, 0, 0);
    }

    // C/D layout: col = lane&15, row = (lane>>4)*4 + reg
    const int crow = (lane >> 4) * 4;
    #pragma unroll
    for (int j = 0; j < 4; ++j) {
        const int n = n0 + j * 16 + lr;
        const float bb = b_obj[n];
        #pragma unroll
        for (int i = 0; i < 4; ++i) {
            #pragma unroll
            for (int r = 0; r < 4; ++r)
                att_obj[(size_t)(m0 + i * 16 + crow + r) * HH + n] = acc[i][j][r] + bb;
        }
    }
}

// ---------- kernel 3: fused tanh-score + softmax + masked renorm + pooling ----------
// ONE WAVE PER ROW. 4 rows per 256-thread block. No LDS, no barriers.
__global__ __launch_bounds__(256) void k_attn(const float* __restrict__ att_obj,   // [6400][512] f32
                                              const float* __restrict__ p_attr,    // [6400][16][512]
                                              const int* __restrict__ masks,       // [6400][16]
                                              const float* __restrict__ w_alpha,   // [512]
                                              const float* __restrict__ attr_feats,// [6400][16][1024]
                                              float* __restrict__ out) {           // [6400][1024]
    const int wv   = threadIdx.x >> 6;
    const int lane = threadIdx.x & 63;
    const int row  = blockIdx.x * 4 + wv;

    // per-lane att_obj / w_alpha slices, loaded once (L1/L2-hot for w_alpha)
    const f32x4* att4 = (const f32x4*)(att_obj + (size_t)row * HH);
    const f32x4* wa4  = (const f32x4*)w_alpha;
    const f32x4 av0 = att4[lane],      av1 = att4[64 + lane];
    const f32x4 wv0 = wa4[lane],       wv1 = wa4[64 + lane];

    // phase 1: per-attr partial dot; lane covers h = (lane*4..+3) and ((64+lane)*4..+3)
    const f32x4* p4 = (const f32x4*)(p_attr + (size_t)row * AA * HH);
    float sc[AA];
    #pragma unroll 4
    for (int a = 0; a < AA; ++a) {
        f32x4 x0 = p4[a * 128 + lane];
        f32x4 x1 = p4[a * 128 + 64 + lane];
        float s;
        s  = wv0.x * fast_tanh(x0.x + av0.x);
        s += wv0.y * fast_tanh(x0.y + av0.y);
        s += wv0.z * fast_tanh(x0.z + av0.z);
        s += wv0.w * fast_tanh(x0.w + av0.w);
        s += wv1.x * fast_tanh(x1.x + av1.x);
        s += wv1.y * fast_tanh(x1.y + av1.y);
        s += wv1.z * fast_tanh(x1.z + av1.z);
        s += wv1.w * fast_tanh(x1.w + av1.w);
        sc[a] = s;
    }

    // cross-lane butterfly: after this every lane holds all 16 full scores
    #pragma unroll
    for (int d = 1; d < 64; d <<= 1) {
        #pragma unroll
        for (int a = 0; a < AA; ++a) sc[a] += __shfl_xor(sc[a], d);
    }

    // phase 2: softmax + mask + renorm, fully lane-local (b_alpha cancels)
    const int4* m4 = (const int4*)(masks + (size_t)row * AA);
    float mk[AA];
    {
        int4 m0v = m4[0], m1v = m4[1], m2v = m4[2], m3v = m4[3];
        mk[0]=(float)m0v.x; mk[1]=(float)m0v.y; mk[2]=(float)m0v.z; mk[3]=(float)m0v.w;
        mk[4]=(float)m1v.x; mk[5]=(float)m1v.y; mk[6]=(float)m1v.z; mk[7]=(float)m1v.w;
        mk[8]=(float)m2v.x; mk[9]=(float)m2v.y; mk[10]=(float)m2v.z; mk[11]=(float)m2v.w;
        mk[12]=(float)m3v.x; mk[13]=(float)m3v.y; mk[14]=(float)m3v.z; mk[15]=(float)m3v.w;
    }
    float mx = sc[0];
    #pragma unroll
    for (int a = 1; a < AA; ++a) mx = fmaxf(mx, sc[a]);
    float S = 0.f, T = 0.f;
    #pragma unroll
    for (int a = 0; a < AA; ++a) {
        float e = __expf(sc[a] - mx);
        sc[a] = e * mk[a];
        S += e;
        T += sc[a];
    }
    const float inv = 1.0f / (T + EPS * S);
    #pragma unroll
    for (int a = 0; a < AA; ++a) sc[a] *= inv;

    // phase 3: streaming weighted pooling; lane owns float4 slots {c*64+lane}
    const f32x4* af4 = (const f32x4*)(attr_feats + (size_t)row * AA * DD);
    f32x4 acc0 = {0.f,0.f,0.f,0.f}, acc1 = acc0, acc2 = acc0, acc3 = acc0;
    #pragma unroll 4
    for (int a = 0; a < AA; ++a) {
        f32x4 v0 = af4[a * 256 +       lane];
        f32x4 v1 = af4[a * 256 +  64 + lane];
        f32x4 v2 = af4[a * 256 + 128 + lane];
        f32x4 v3 = af4[a * 256 + 192 + lane];
        const float w = sc[a];
        acc0 += w * v0;
        acc1 += w * v1;
        acc2 += w * v2;
        acc3 += w * v3;
    }
    f32x4* o4 = (f32x4*)(out + (size_t)row * DD);
    o4[      lane] = acc0;
    o4[ 64 + lane] = acc1;
    o4[128 + lane] = acc2;
    o4[192 + lane] = acc3;
}

extern "C" void kernel_launch(void* const* d_in, const int* in_sizes, int n_in,
                              void* d_out, int out_size, void* d_ws, size_t ws_size,
                              hipStream_t stream) {
    const float* obj_vecs   = (const float*)d_in[0];
    const float* attr_feats = (const float*)d_in[1];
    const float* p_attr     = (const float*)d_in[2];
    const int*   masks      = (const int*)d_in[3];
    const float* W_obj      = (const float*)d_in[4];
    const float* b_obj      = (const float*)d_in[5];
    const float* w_alpha    = (const float*)d_in[6];
    // d_in[7] = b_alpha: uniform additive shift before softmax -> cancels exactly
    float* out = (float*)d_out;

    char* ws = (char*)d_ws;
    float*          att_obj = (float*)ws;                                   // 13,107,200 B
    unsigned short* obj_bf  = (unsigned short*)(ws + 13107200);             // 13,107,200 B
    unsigned short* W_bf    = (unsigned short*)(ws + 13107200 + 13107200);  //  1,048,576 B
    // total ws use: 27,262,976 B

    k_prep<<<3456, 256, 0, stream>>>(obj_vecs, W_obj, obj_bf, W_bf);
    k_gemm<<<800, 64, 0, stream>>>(obj_bf, W_bf, b_obj, att_obj);
    k_attn<<<BO / 4, 256, 0, stream>>>(att_obj, p_attr, masks, w_alpha, attr_feats, out);
}

// Round 3
// 165.835 us; speedup vs baseline: 1.2506x; 1.0716x over previous
//
#include <hip/hip_runtime.h>
#include <stdint.h>

#define EPS 1e-8f

typedef __attribute__((ext_vector_type(8))) __bf16 bf16x8;
typedef __attribute__((ext_vector_type(4))) float f32x4;

static constexpr int BO = 6400;   // B*O
static constexpr int AA = 16;     // attributes
static constexpr int DD = 1024;   // D
static constexpr int HH = 512;    // H

// ---------- helpers ----------
__device__ __forceinline__ unsigned short f2bf(float x) {
    uint32_t b = __float_as_uint(x);
    b += 0x7fffu + ((b >> 16) & 1u);   // round-to-nearest-even (finite inputs)
    return (unsigned short)(b >> 16);
}

__device__ __forceinline__ float fast_tanh(float x) {
    // tanh(x) = 1 - 2/(exp(2x)+1); exp overflow -> inf -> rcp -> 0 -> +1 (correct)
    float e = __expf(2.0f * x);
    return 1.0f - __fdividef(2.0f, e + 1.0f);
}

// ---------- kernel 1: f32 -> bf16 staging of W_obj only (obj handled in k_gemm) ----------
__global__ __launch_bounds__(256) void k_prep_w(const float* __restrict__ W,
                                                unsigned short* __restrict__ W_bf) {
    const int i = blockIdx.x * 256 + threadIdx.x;   // 65536 8-elem units
    const long off = (long)i * 8;
    float4 v0 = *(const float4*)(W + off);
    float4 v1 = *(const float4*)(W + off + 4);
    union { unsigned short u[8]; int4 v; } pk;
    pk.u[0] = f2bf(v0.x); pk.u[1] = f2bf(v0.y); pk.u[2] = f2bf(v0.z); pk.u[3] = f2bf(v0.w);
    pk.u[4] = f2bf(v1.x); pk.u[5] = f2bf(v1.y); pk.u[6] = f2bf(v1.z); pk.u[7] = f2bf(v1.w);
    *(int4*)(W_bf + off) = pk.v;
}

// ---------- kernel 2: att_obj[6400][512] = obj @ W^T + b_obj, f32 out ----------
// one wave per block; 64x64 output tile (4x4 MFMA frags); A read f32 + converted in-regs.
// XCD-aware remap: hardware round-robins block b -> XCD b%8; give each XCD a contiguous
// 13-mt strip x all 8 nt so its A-chunk (3.3 MB f32) + B (1 MB) stay L2-resident.
__global__ __launch_bounds__(64) void k_gemm(const float* __restrict__ obj,            // [6400][1024] f32
                                             const unsigned short* __restrict__ W_bf,  // [512][1024]  bf16
                                             const float* __restrict__ b_obj,          // [512]
                                             float* __restrict__ att_obj) {            // [6400][512]  f32
    const int lane = threadIdx.x;
    const int xcd  = blockIdx.x & 7;
    const int j    = blockIdx.x >> 3;        // 0..103
    const int mt   = xcd * 13 + (j % 13);    // 0..103
    if (mt >= 100) return;                   // 32 idle blocks on xcd 7
    const int nt   = j / 13;                 // 0..7
    const int m0   = mt * 64;
    const int n0   = nt * 64;
    const int lr   = lane & 15;
    const int lk   = (lane >> 4) * 8;

    const float*          ap = obj  + (size_t)(m0 + lr) * DD + lk;
    const unsigned short* bp = W_bf + (size_t)(n0 + lr) * DD + lk;

    f32x4 acc[4][4];
    #pragma unroll
    for (int i = 0; i < 4; ++i)
        #pragma unroll
        for (int jj = 0; jj < 4; ++jj) acc[i][jj] = f32x4{0.f, 0.f, 0.f, 0.f};

    // 2-deep software pipeline: prefetch k+32 while MFMA on k
    float4 a_lo[4], a_hi[4];
    bf16x8 bfr[4];
    #pragma unroll
    for (int i = 0; i < 4; ++i) {
        a_lo[i] = *(const float4*)(ap + (size_t)i * 16 * DD);
        a_hi[i] = *(const float4*)(ap + (size_t)i * 16 * DD + 4);
        bfr[i]  = *(const bf16x8*)(bp + (size_t)i * 16 * DD);
    }

    #pragma unroll 1
    for (int k0 = 0; k0 < DD; k0 += 32) {
        const int kn = (k0 + 32 < DD) ? (k0 + 32) : 0;   // clamp: no OOB on input buffer
        float4 na_lo[4], na_hi[4];
        bf16x8 nb[4];
        #pragma unroll
        for (int i = 0; i < 4; ++i) {
            na_lo[i] = *(const float4*)(ap + (size_t)i * 16 * DD + kn);
            na_hi[i] = *(const float4*)(ap + (size_t)i * 16 * DD + kn + 4);
            nb[i]    = *(const bf16x8*)(bp + (size_t)i * 16 * DD + kn);
        }
        bf16x8 afr[4];
        #pragma unroll
        for (int i = 0; i < 4; ++i) {
            afr[i][0] = (__bf16)a_lo[i].x; afr[i][1] = (__bf16)a_lo[i].y;
            afr[i][2] = (__bf16)a_lo[i].z; afr[i][3] = (__bf16)a_lo[i].w;
            afr[i][4] = (__bf16)a_hi[i].x; afr[i][5] = (__bf16)a_hi[i].y;
            afr[i][6] = (__bf16)a_hi[i].z; afr[i][7] = (__bf16)a_hi[i].w;
        }
        #pragma unroll
        for (int i = 0; i < 4; ++i)
            #pragma unroll
            for (int jj = 0; jj < 4; ++jj)
                acc[i][jj] = __builtin_amdgcn_mfma_f32_16x16x32_bf16(afr[i], bfr[jj], acc[i][jj], 0, 0, 0);
        #pragma unroll
        for (int i = 0; i < 4; ++i) { a_lo[i] = na_lo[i]; a_hi[i] = na_hi[i]; bfr[i] = nb[i]; }
    }

    // C/D layout: col = lane&15, row = (lane>>4)*4 + reg
    const int crow = (lane >> 4) * 4;
    #pragma unroll
    for (int jj = 0; jj < 4; ++jj) {
        const int n = n0 + jj * 16 + lr;
        const float bb = b_obj[n];
        #pragma unroll
        for (int i = 0; i < 4; ++i) {
            #pragma unroll
            for (int r = 0; r < 4; ++r)
                att_obj[(size_t)(m0 + i * 16 + crow + r) * HH + n] = acc[i][jj][r] + bb;
        }
    }
}

// ---------- kernel 3: fused tanh-score + softmax + masked renorm + pooling ----------
// ONE WAVE PER ROW. 4 rows per 256-thread block. No LDS, no barriers.
// Streaming inputs (p_attr, attr_feats) and output use nontemporal hints (zero reuse).
__global__ __launch_bounds__(256) void k_attn(const float* __restrict__ att_obj,   // [6400][512] f32
                                              const float* __restrict__ p_attr,    // [6400][16][512]
                                              const int* __restrict__ masks,       // [6400][16]
                                              const float* __restrict__ w_alpha,   // [512]
                                              const float* __restrict__ attr_feats,// [6400][16][1024]
                                              float* __restrict__ out) {           // [6400][1024]
    const int wv   = threadIdx.x >> 6;
    const int lane = threadIdx.x & 63;
    const int row  = blockIdx.x * 4 + wv;

    // per-lane att_obj / w_alpha slices, loaded once (w_alpha L2-hot)
    const f32x4* att4 = (const f32x4*)(att_obj + (size_t)row * HH);
    const f32x4* wa4  = (const f32x4*)w_alpha;
    const f32x4 av0 = att4[lane],      av1 = att4[64 + lane];
    const f32x4 wv0 = wa4[lane],       wv1 = wa4[64 + lane];

    // phase 1: per-attr partial dot; lane covers h = (lane*4..+3) and ((64+lane)*4..+3)
    const f32x4* p4 = (const f32x4*)(p_attr + (size_t)row * AA * HH);
    float sc[AA];
    #pragma unroll 4
    for (int a = 0; a < AA; ++a) {
        f32x4 x0 = __builtin_nontemporal_load(&p4[a * 128 + lane]);
        f32x4 x1 = __builtin_nontemporal_load(&p4[a * 128 + 64 + lane]);
        float s;
        s  = wv0.x * fast_tanh(x0.x + av0.x);
        s += wv0.y * fast_tanh(x0.y + av0.y);
        s += wv0.z * fast_tanh(x0.z + av0.z);
        s += wv0.w * fast_tanh(x0.w + av0.w);
        s += wv1.x * fast_tanh(x1.x + av1.x);
        s += wv1.y * fast_tanh(x1.y + av1.y);
        s += wv1.z * fast_tanh(x1.z + av1.z);
        s += wv1.w * fast_tanh(x1.w + av1.w);
        sc[a] = s;
    }

    // cross-lane butterfly: after this every lane holds all 16 full scores
    #pragma unroll
    for (int d = 1; d < 64; d <<= 1) {
        #pragma unroll
        for (int a = 0; a < AA; ++a) sc[a] += __shfl_xor(sc[a], d);
    }

    // phase 2: softmax + mask + renorm, fully lane-local (b_alpha cancels)
    const int4* m4 = (const int4*)(masks + (size_t)row * AA);
    float mk[AA];
    {
        int4 m0v = m4[0], m1v = m4[1], m2v = m4[2], m3v = m4[3];
        mk[0]=(float)m0v.x; mk[1]=(float)m0v.y; mk[2]=(float)m0v.z; mk[3]=(float)m0v.w;
        mk[4]=(float)m1v.x; mk[5]=(float)m1v.y; mk[6]=(float)m1v.z; mk[7]=(float)m1v.w;
        mk[8]=(float)m2v.x; mk[9]=(float)m2v.y; mk[10]=(float)m2v.z; mk[11]=(float)m2v.w;
        mk[12]=(float)m3v.x; mk[13]=(float)m3v.y; mk[14]=(float)m3v.z; mk[15]=(float)m3v.w;
    }
    float mx = sc[0];
    #pragma unroll
    for (int a = 1; a < AA; ++a) mx = fmaxf(mx, sc[a]);
    float S = 0.f, T = 0.f;
    #pragma unroll
    for (int a = 0; a < AA; ++a) {
        float e = __expf(sc[a] - mx);
        sc[a] = e * mk[a];
        S += e;
        T += sc[a];
    }
    const float inv = 1.0f / (T + EPS * S);
    #pragma unroll
    for (int a = 0; a < AA; ++a) sc[a] *= inv;

    // phase 3: streaming weighted pooling; lane owns float4 slots {c*64+lane}
    const f32x4* af4 = (const f32x4*)(attr_feats + (size_t)row * AA * DD);
    f32x4 acc0 = {0.f,0.f,0.f,0.f}, acc1 = acc0, acc2 = acc0, acc3 = acc0;
    #pragma unroll 4
    for (int a = 0; a < AA; ++a) {
        f32x4 v0 = __builtin_nontemporal_load(&af4[a * 256 +       lane]);
        f32x4 v1 = __builtin_nontemporal_load(&af4[a * 256 +  64 + lane]);
        f32x4 v2 = __builtin_nontemporal_load(&af4[a * 256 + 128 + lane]);
        f32x4 v3 = __builtin_nontemporal_load(&af4[a * 256 + 192 + lane]);
        const float w = sc[a];
        acc0 += w * v0;
        acc1 += w * v1;
        acc2 += w * v2;
        acc3 += w * v3;
    }
    f32x4* o4 = (f32x4*)(out + (size_t)row * DD);
    __builtin_nontemporal_store(acc0, &o4[      lane]);
    __builtin_nontemporal_store(acc1, &o4[ 64 + lane]);
    __builtin_nontemporal_store(acc2, &o4[128 + lane]);
    __builtin_nontemporal_store(acc3, &o4[192 + lane]);
}

extern "C" void kernel_launch(void* const* d_in, const int* in_sizes, int n_in,
                              void* d_out, int out_size, void* d_ws, size_t ws_size,
                              hipStream_t stream) {
    const float* obj_vecs   = (const float*)d_in[0];
    const float* attr_feats = (const float*)d_in[1];
    const float* p_attr     = (const float*)d_in[2];
    const int*   masks      = (const int*)d_in[3];
    const float* W_obj      = (const float*)d_in[4];
    const float* b_obj      = (const float*)d_in[5];
    const float* w_alpha    = (const float*)d_in[6];
    // d_in[7] = b_alpha: uniform additive shift before softmax -> cancels exactly
    float* out = (float*)d_out;

    char* ws = (char*)d_ws;
    float*          att_obj = (float*)ws;                       // 13,107,200 B
    unsigned short* W_bf    = (unsigned short*)(ws + 13107200); //  1,048,576 B
    // total ws use: 14,155,776 B

    k_prep_w<<<256, 256, 0, stream>>>(W_obj, W_bf);
    k_gemm<<<832, 64, 0, stream>>>(obj_vecs, W_bf, b_obj, att_obj);
    k_attn<<<BO / 4, 256, 0, stream>>>(att_obj, p_attr, masks, w_alpha, attr_feats, out);
}